// Round 17
// baseline (1829.645 us; speedup 1.0000x reference)
//
#include <hip/hip_runtime.h>

typedef unsigned int u32;
typedef unsigned long long u64;
typedef __fp16 f16;
typedef __fp16 h2 __attribute__((ext_vector_type(2)));
typedef __fp16 h4 __attribute__((ext_vector_type(4)));
typedef __fp16 h8 __attribute__((ext_vector_type(8)));
typedef float f32x2v __attribute__((ext_vector_type(2)));
typedef float f32x4v __attribute__((ext_vector_type(4)));
typedef float f32x16v __attribute__((ext_vector_type(16)));
typedef u32 u32x2v __attribute__((ext_vector_type(2)));
typedef u32 u32x4v __attribute__((ext_vector_type(4)));

static constexpr int BB = 64;     // batch
static constexpr int TT = 1024;   // seq len
static constexpr int HH = 256;    // hidden
static constexpr int GG = 768;    // 3*H
static constexpr size_t GI_BYTES = (size_t)BB * TT * GG * 2;  // f16 gi buffer

__device__ __forceinline__ u32 pk2(float a, float b) {
  h2 r = __builtin_amdgcn_cvt_pkrtz(a, b);
  return __builtin_bit_cast(u32, r);
}
__device__ __forceinline__ float dpp_shr8(float x) {  // row_shr:8 -> dst[i]=src[i-8]
  return __builtin_bit_cast(float,
      __builtin_amdgcn_mov_dpp(__builtin_bit_cast(int, x), 0x118, 0xF, 0xF, true));
}
__device__ __forceinline__ float sigf(float x) { return 1.f / (1.f + __expf(-x)); }
__device__ __forceinline__ float tanhf2(float x) {
  float e = __expf(2.f * x);
  return 1.f - 2.f / (e + 1.f);
}

// ---------------------------------------------------------------------------
// Phase 0: prepack W_hh into MFMA A-fragment order (r7 layout, passed).
// Wave w tile m = G*16 + 2w + tj (ti6 = G*2+tj), frag f = ti6*8 + ks,
// lane l: row = 16m + (l&15), k = 32ks + 8(l>>4) + 2e2.
// Wa dword = (w*64+l)*192 + f*4 + e2  -> per-thread contiguous (r12 loader).
// Weight frag f lives in physical VGPR 64 + f*4 .. +3.
// ---------------------------------------------------------------------------
__global__ void prepack_wa(const float* __restrict__ Whh, u32* __restrict__ Wa) {
  int id = blockIdx.x * 256 + threadIdx.x;  // [0, 98304)
  int lane_g = id / 192;
  int rrem = id - lane_g * 192;
  int f = rrem >> 2, e2 = rrem & 3;
  int ti6 = f >> 3, ks = f & 7;
  int G = ti6 >> 1, tj = ti6 & 1;
  int w = lane_g >> 6, l = lane_g & 63;
  int m = G * 16 + 2 * w + tj;
  int row = 16 * m + (l & 15);
  int k = 32 * ks + 8 * (l >> 4) + 2 * e2;
  const float* p = Whh + (size_t)row * HH + k;
  Wa[id] = pk2(p[0], p[1]);
}

// ---------------------------------------------------------------------------
// Phase 1: gi = x @ W_ih^T + b_ih (+ b_hh folded for r,z), f16. (unchanged)
// ---------------------------------------------------------------------------
__device__ __forceinline__ f32x16v zero16() {
  f32x16v z;
#pragma unroll
  for (int i = 0; i < 16; ++i) z[i] = 0.f;
  return z;
}

__global__ __launch_bounds__(256, 2) void gemm_gi(
    const float* __restrict__ x, const float* __restrict__ Wih,
    const float* __restrict__ bih, const float* __restrict__ bhh,
    f16* __restrict__ gi) {
  __shared__ u32 bl[16384];
  const int tid = threadIdx.x;
  const int lane = tid & 63;
  const int wv = tid >> 6;
  const int wr = wv >> 1, wc = wv & 1;
  const int l31 = lane & 31, lh = lane >> 5;
  const int m0 = blockIdx.x << 7;

  u32x4v afr[2][16];
#pragma unroll
  for (int fr = 0; fr < 2; ++fr) {
#pragma unroll
    for (int km = 0; km < 16; ++km) {
      int row = m0 + wr * 64 + fr * 32 + l31;
      int k0 = km * 16 + lh * 8;
      const f32x4v* p = (const f32x4v*)(x + (size_t)row * 256 + k0);
      f32x4v u = p[0], v = p[1];
      u32x4v t;
      t.x = pk2(u.x, u.y); t.y = pk2(u.z, u.w);
      t.z = pk2(v.x, v.y); t.w = pk2(v.z, v.w);
      afr[fr][km] = t;
    }
  }

  for (int nt = 0; nt < 6; ++nt) {
    const int n0 = nt << 7;
#pragma unroll
    for (int it = 0; it < 32; ++it) {
      int flat = it * 256 + tid;
      int r = flat >> 6;
      int q = flat & 63;
      f32x4v f = *(const f32x4v*)(Wih + (size_t)(n0 + r) * 256 + 4 * q);
      u32x2v pw;
      pw.x = pk2(f.x, f.y);
      pw.y = pk2(f.z, f.w);
      int wd = 2 * q;
      *(u32x2v*)&bl[r * 128 + (wd ^ ((r & 15) << 2))] = pw;
    }
    __syncthreads();

    f32x16v acc00 = zero16(), acc01 = zero16(), acc10 = zero16(), acc11 = zero16();
#pragma unroll
    for (int km = 0; km < 16; ++km) {
      int w0 = km * 8 + lh * 4;
      int rc0 = wc * 64 + l31;
      int rc1 = wc * 64 + 32 + l31;
      u32x4v b0 = *(const u32x4v*)&bl[rc0 * 128 + (w0 ^ ((rc0 & 15) << 2))];
      u32x4v b1 = *(const u32x4v*)&bl[rc1 * 128 + (w0 ^ ((rc1 & 15) << 2))];
      h8 a0h = __builtin_bit_cast(h8, afr[0][km]);
      h8 a1h = __builtin_bit_cast(h8, afr[1][km]);
      h8 b0h = __builtin_bit_cast(h8, b0);
      h8 b1h = __builtin_bit_cast(h8, b1);
      acc00 = __builtin_amdgcn_mfma_f32_32x32x16_f16(a0h, b0h, acc00, 0, 0, 0);
      acc10 = __builtin_amdgcn_mfma_f32_32x32x16_f16(a1h, b0h, acc10, 0, 0, 0);
      acc01 = __builtin_amdgcn_mfma_f32_32x32x16_f16(a0h, b1h, acc01, 0, 0, 0);
      acc11 = __builtin_amdgcn_mfma_f32_32x32x16_f16(a1h, b1h, acc11, 0, 0, 0);
    }

#define EPI(ACC, FR, FC)                                                      \
    {                                                                         \
      int gc = n0 + wc * 64 + (FC) * 32 + l31;                                \
      float bias = bih[gc] + (gc < 512 ? bhh[gc] : 0.f);                      \
      _Pragma("unroll")                                                       \
      for (int rg = 0; rg < 16; ++rg) {                                       \
        int gr = m0 + wr * 64 + (FR) * 32 + 4 * lh + (rg & 3) + 8 * (rg >> 2);\
        gi[(size_t)gr * 768 + gc] = (f16)(ACC[rg] + bias);                    \
      }                                                                       \
    }
    EPI(acc00, 0, 0) EPI(acc10, 1, 0) EPI(acc01, 0, 1) EPI(acc11, 1, 1)
#undef EPI
    __syncthreads();
  }
}

// ---------------------------------------------------------------------------
// Phase 2: recurrence, ALL-VGPR physical MFMA core (no AGPRs anywhere).
// 8 blocks x 8 batches, 512 thr (8 waves, 2/SIMD, 256 VGPR exactly):
//   v0..v23   : C-side compiler-allocated state
//   v24..v39  : 4 rotating B-fragment buffers (counted-lgkmcnt pipeline)
//   v40..v63  : 6 accumulator tiles (f32x4), zeroed per step via v_mov
//   v64..v255 : 48 weight A-fragments, loaded once by the r12-proven loader
// MFMA = literal-register asm, all operands VGPR (gfx950 unified file).
// Gate/rebalance/hb layout verbatim from r7 (passed, absmax 0.0156).
// ---------------------------------------------------------------------------
#define WCLOB_LD \
  "v64","v65","v66","v67","v68","v69","v70","v71", \
  "v72","v73","v74","v75","v76","v77","v78","v79", \
  "v80","v81","v82","v83","v84","v85","v86","v87", \
  "v88","v89","v90","v91","v92","v93","v94","v95", \
  "v96","v97","v98","v99","v100","v101","v102","v103", \
  "v104","v105","v106","v107","v108","v109","v110","v111", \
  "v112","v113","v114","v115","v116","v117","v118","v119", \
  "v120","v121","v122","v123","v124","v125","v126","v127", \
  "v128","v129","v130","v131","v132","v133","v134","v135", \
  "v136","v137","v138","v139","v140","v141","v142","v143", \
  "v144","v145","v146","v147","v148","v149","v150","v151", \
  "v152","v153","v154","v155","v156","v157","v158","v159", \
  "v160","v161","v162","v163","v164","v165","v166","v167", \
  "v168","v169","v170","v171","v172","v173","v174","v175", \
  "v176","v177","v178","v179","v180","v181","v182","v183", \
  "v184","v185","v186","v187","v188","v189","v190","v191", \
  "v192","v193","v194","v195","v196","v197","v198","v199", \
  "v200","v201","v202","v203","v204","v205","v206","v207", \
  "v208","v209","v210","v211","v212","v213","v214","v215", \
  "v216","v217","v218","v219","v220","v221","v222","v223", \
  "v224","v225","v226","v227","v228","v229","v230","v231", \
  "v232","v233","v234","v235","v236","v237","v238","v239", \
  "v240","v241","v242","v243","v244","v245","v246","v247", \
  "v248","v249","v250","v251","v252","v253","v254","v255"

#define VCLOB_MID \
  "v24","v25","v26","v27","v28","v29","v30","v31", \
  "v32","v33","v34","v35","v36","v37","v38","v39", \
  "v40","v41","v42","v43","v44","v45","v46","v47", \
  "v48","v49","v50","v51","v52","v53","v54","v55", \
  "v56","v57","v58","v59","v60","v61","v62","v63"

#define LD16(A,B,OFF) "global_load_dwordx4 v[" #A ":" #B "], %0, off offset:" #OFF "\n\t"

// 6 MFMAs: one B fragment against the 6 tile-rows' A frags of this K-slice.
// acc tiles fixed: ti6=0..5 -> v[40:43],[44:47],[48:51],[52:55],[56:59],[60:63]
#define MFMA6(B0,B1, S0,E0, S1,E1, S2,E2, S3,E3, S4,E4, S5,E5) \
  "v_mfma_f32_16x16x32_f16 v[40:43], v[" #S0 ":" #E0 "], v[" #B0 ":" #B1 "], v[40:43]\n\t" \
  "v_mfma_f32_16x16x32_f16 v[44:47], v[" #S1 ":" #E1 "], v[" #B0 ":" #B1 "], v[44:47]\n\t" \
  "v_mfma_f32_16x16x32_f16 v[48:51], v[" #S2 ":" #E2 "], v[" #B0 ":" #B1 "], v[48:51]\n\t" \
  "v_mfma_f32_16x16x32_f16 v[52:55], v[" #S3 ":" #E3 "], v[" #B0 ":" #B1 "], v[52:55]\n\t" \
  "v_mfma_f32_16x16x32_f16 v[56:59], v[" #S4 ":" #E4 "], v[" #B0 ":" #B1 "], v[56:59]\n\t" \
  "v_mfma_f32_16x16x32_f16 v[60:63], v[" #S5 ":" #E5 "], v[" #B0 ":" #B1 "], v[60:63]\n\t"

#define VZ(N) "v_mov_b32 v" #N ", 0\n\t"

// read the 6 acc values of one D-row (row r: regs v[40+r], v[44+r], ...)
#define ROWR(A0,A1,A2,A3,A4,A5, O0,O1,O2,O3,O4,O5)           \
  asm volatile("v_mov_b32 %0, v" #A0 "\n\t"                  \
               "v_mov_b32 %1, v" #A1 "\n\t"                  \
               "v_mov_b32 %2, v" #A2 "\n\t"                  \
               "v_mov_b32 %3, v" #A3 "\n\t"                  \
               "v_mov_b32 %4, v" #A4 "\n\t"                  \
               "v_mov_b32 %5, v" #A5                         \
               : "=v"(O0), "=v"(O1), "=v"(O2),               \
                 "=v"(O3), "=v"(O4), "=v"(O5))

__global__ __launch_bounds__(512, 2) void recur(
    const u32* __restrict__ Wa, const f16* __restrict__ gi,
    const float* __restrict__ states, const float* __restrict__ mask,
    const float* __restrict__ bhh_g, float* __restrict__ out) {
  const int blk = blockIdx.x;          // 0..7
  const int tid = threadIdx.x;
  const int w = tid >> 6, l = tid & 63;
  const int lr = l & 15, g = l >> 4;
  const int c = lr & 7, tj = lr >> 3;
  const bool hi = (lr >= 8);
  const int u0 = 32 * w + 16 * tj + 4 * g;
  const int bb = blk * 8 + c;

  __shared__ __align__(16) f16 hb[2][4096];  // B-frag order, cols 8..15 zero
  __shared__ f16 mlds[8192];                 // [t][batch8]
  __shared__ f16 bn16[256];                  // b_hh n-gate (f16)

  // ---- stage mask, n-bias, h0 (BEFORE weight loader clobbers v64+) ----
  for (int idx = tid; idx < 8192; idx += 512) {
    int b8 = idx >> 10, tt = idx & 1023;
    mlds[tt * 8 + b8] = (f16)mask[(size_t)(blk * 8 + b8) * TT + tt];
  }
  if (tid < 256) bn16[tid] = (f16)bhh_g[512 + tid];
  for (int idx = tid; idx < 4096; idx += 512) {
    int unit = idx >> 4, cc = idx & 15;
    float v = 0.f;
    if (cc < 8)
      v = states[(size_t)(blk * 8 + cc) * HH + unit] *
          mask[(size_t)(blk * 8 + cc) * TT];
    int fa = (unit >> 5) * 512 + ((unit >> 3) & 3) * 128 + cc * 8 + (unit & 7);
    hb[0][fa] = (f16)v;
    hb[1][fa] = (f16)v;
  }

  // ---- load 192 weight dwords into PHYSICAL v64..v255 (r12-proven) ----
  {
    u64 wa = (u64)(Wa + (size_t)tid * 192);
    asm volatile(
      LD16(64,67,0)    LD16(68,71,16)   LD16(72,75,32)   LD16(76,79,48)
      LD16(80,83,64)   LD16(84,87,80)   LD16(88,91,96)   LD16(92,95,112)
      LD16(96,99,128)  LD16(100,103,144) LD16(104,107,160) LD16(108,111,176)
      LD16(112,115,192) LD16(116,119,208) LD16(120,123,224) LD16(124,127,240)
      LD16(128,131,256) LD16(132,135,272) LD16(136,139,288) LD16(140,143,304)
      LD16(144,147,320) LD16(148,151,336) LD16(152,155,352) LD16(156,159,368)
      LD16(160,163,384) LD16(164,167,400) LD16(168,171,416) LD16(172,175,432)
      LD16(176,179,448) LD16(180,183,464) LD16(184,187,480) LD16(188,191,496)
      LD16(192,195,512) LD16(196,199,528) LD16(200,203,544) LD16(204,207,560)
      LD16(208,211,576) LD16(212,215,592) LD16(216,219,608) LD16(220,223,624)
      LD16(224,227,640) LD16(228,231,656) LD16(232,235,672) LD16(236,239,688)
      LD16(240,243,704) LD16(244,247,720) LD16(248,251,736) LD16(252,255,752)
      "s_waitcnt vmcnt(0)\n\t"
      :: "v"(wa) : WCLOB_LD, "memory");
  }
  __syncthreads();

  const f16* gip = gi + (size_t)bb * TT * GG + u0;
  float* outp = out + (size_t)bb * TT * HH + u0;
  const int fa0 = w * 512 + ((2 * tj + (g >> 1)) & 3) * 128 + c * 8 + 4 * (g & 1);
  const int rbase_b = (g * 128 + lr * 8) * 2;  // byte offset of B-frag base

  for (int t = 0; t < TT; ++t) {
    // gi loads issued before the MFMA phase (latency hides under it)
    const f16* gt = gip + (size_t)t * GG;
    h4 gr4 = *(const h4*)(gt);
    h4 gz4 = *(const h4*)(gt + 256);
    h4 gn4 = *(const h4*)(gt + 512);

    u32 la = (u32)(size_t)(&hb[t & 1][0]) + rbase_b;

    asm volatile(
      "s_waitcnt lgkmcnt(0)\n\t"
      VZ(40) VZ(41) VZ(42) VZ(43) VZ(44) VZ(45) VZ(46) VZ(47)
      VZ(48) VZ(49) VZ(50) VZ(51) VZ(52) VZ(53) VZ(54) VZ(55)
      VZ(56) VZ(57) VZ(58) VZ(59) VZ(60) VZ(61) VZ(62) VZ(63)
      "ds_read_b128 v[24:27], %0 offset:0\n\t"
      "ds_read_b128 v[28:31], %0 offset:1024\n\t"
      "ds_read_b128 v[32:35], %0 offset:2048\n\t"
      "ds_read_b128 v[36:39], %0 offset:3072\n\t"
      "s_waitcnt lgkmcnt(3)\n\t"
      MFMA6(24,27, 64,67, 96,99, 128,131, 160,163, 192,195, 224,227)
      "ds_read_b128 v[24:27], %0 offset:4096\n\t"
      "s_waitcnt lgkmcnt(3)\n\t"
      MFMA6(28,31, 68,71, 100,103, 132,135, 164,167, 196,199, 228,231)
      "ds_read_b128 v[28:31], %0 offset:5120\n\t"
      "s_waitcnt lgkmcnt(3)\n\t"
      MFMA6(32,35, 72,75, 104,107, 136,139, 168,171, 200,203, 232,235)
      "ds_read_b128 v[32:35], %0 offset:6144\n\t"
      "s_waitcnt lgkmcnt(3)\n\t"
      MFMA6(36,39, 76,79, 108,111, 140,143, 172,175, 204,207, 236,239)
      "ds_read_b128 v[36:39], %0 offset:7168\n\t"
      "s_waitcnt lgkmcnt(3)\n\t"
      MFMA6(24,27, 80,83, 112,115, 144,147, 176,179, 208,211, 240,243)
      "s_waitcnt lgkmcnt(2)\n\t"
      MFMA6(28,31, 84,87, 116,119, 148,151, 180,183, 212,215, 244,247)
      "s_waitcnt lgkmcnt(1)\n\t"
      MFMA6(32,35, 88,91, 120,123, 152,155, 184,187, 216,219, 248,251)
      "s_waitcnt lgkmcnt(0)\n\t"
      MFMA6(36,39, 92,95, 124,127, 156,159, 188,191, 220,223, 252,255)
      "s_nop 7\n\t"
      "s_nop 7\n\t"
      "s_nop 7\n\t"
      :: "v"(la) : VCLOB_MID, WCLOB_LD, "memory");

    const float mt = (float)mlds[t * 8 + c];
    h4 hold4 = *(const h4*)&hb[t & 1][fa0];
    h4 bnh = *(const h4*)&bn16[u0];

    f32x4v nh4;
    h4 hnew4;
#pragma unroll
    for (int r = 0; r < 4; ++r) {
      float ac0, ac1, ac2, ac3, ac4, ac5;
      if (r == 0) ROWR(40,44,48,52,56,60, ac0,ac1,ac2,ac3,ac4,ac5);
      if (r == 1) ROWR(41,45,49,53,57,61, ac0,ac1,ac2,ac3,ac4,ac5);
      if (r == 2) ROWR(42,46,50,54,58,62, ac0,ac1,ac2,ac3,ac4,ac5);
      if (r == 3) ROWR(43,47,51,55,59,63, ac0,ac1,ac2,ac3,ac4,ac5);
      float d0 = dpp_shr8(ac1), d1 = dpp_shr8(ac3), d2 = dpp_shr8(ac5);
      float vr = hi ? d0 : ac0;
      float vz = hi ? d1 : ac2;
      float vn = hi ? d2 : ac4;
      float hold = (float)hold4[r];
      float rr = sigf((float)gr4[r] + vr);
      float zz = sigf((float)gz4[r] + vz);
      float nn = tanhf2((float)gn4[r] + rr * (vn + (float)bnh[r]));
      float nh = zz * (hold - nn) + nn;
      nh4[r] = nh;
      hnew4[r] = (f16)(hold + mt * (nh - hold));
    }
    *(f32x4v*)(outp + (size_t)t * HH) = nh4;
    *(u32x2v*)&hb[(t + 1) & 1][fa0] = __builtin_bit_cast(u32x2v, hnew4);
    __syncthreads();
  }

  // final state from hb[TT&1] = hb[0]
  {
    h4 hf = *(const h4*)&hb[0][fa0];
    f32x4v o;
#pragma unroll
    for (int r = 0; r < 4; ++r) o[r] = (float)hf[r];
    *(f32x4v*)(out + (size_t)BB * TT * HH + (size_t)bb * HH + u0) = o;
  }
}

extern "C" void kernel_launch(void* const* d_in, const int* in_sizes, int n_in,
                              void* d_out, int out_size, void* d_ws, size_t ws_size,
                              hipStream_t stream) {
  const float* x      = (const float*)d_in[0];
  const float* states = (const float*)d_in[1];
  const float* mask   = (const float*)d_in[2];
  const float* W_ih   = (const float*)d_in[3];
  const float* W_hh   = (const float*)d_in[4];
  const float* b_ih   = (const float*)d_in[5];
  const float* b_hh   = (const float*)d_in[6];
  float* out = (float*)d_out;

  char* ws = (char*)d_ws;
  f16* gi = (f16*)ws;
  u32* Wa = (u32*)(ws + GI_BYTES);

  prepack_wa<<<dim3(384), dim3(256), 0, stream>>>(W_hh, Wa);
  gemm_gi<<<dim3(512), dim3(256), 0, stream>>>(x, W_ih, b_ih, b_hh, gi);
  recur<<<dim3(8), dim3(512), 0, stream>>>(Wa, gi, states, mask, b_hh, out);
}

// Round 18
// 1358.808 us; speedup vs baseline: 1.3465x; 1.3465x over previous
//
#include <hip/hip_runtime.h>

typedef unsigned int u32;
typedef unsigned long long u64;
typedef __fp16 f16;
typedef __fp16 h2 __attribute__((ext_vector_type(2)));
typedef __fp16 h8 __attribute__((ext_vector_type(8)));
typedef float f32x2v __attribute__((ext_vector_type(2)));
typedef float f32x4v __attribute__((ext_vector_type(4)));
typedef float f32x16v __attribute__((ext_vector_type(16)));
typedef u32 u32x2v __attribute__((ext_vector_type(2)));
typedef u32 u32x4v __attribute__((ext_vector_type(4)));

static constexpr int BB = 64;     // batch
static constexpr int TT = 1024;   // seq len
static constexpr int HH = 256;    // hidden
static constexpr int GG = 768;    // 3*H
static constexpr size_t GI_BYTES = (size_t)BB * TT * GG * 2;  // f16 gi buffer

__device__ __forceinline__ u32 pk2(float a, float b) {
  h2 r = __builtin_amdgcn_cvt_pkrtz(a, b);
  return __builtin_bit_cast(u32, r);
}
__device__ __forceinline__ float dpp_x1(float x) {  // quad_perm [1,0,3,2]: pair swap
  return __builtin_bit_cast(float,
      __builtin_amdgcn_mov_dpp(__builtin_bit_cast(int, x), 0xB1, 0xF, 0xF, true));
}
__device__ __forceinline__ float sigf(float x) { return 1.f / (1.f + __expf(-x)); }
__device__ __forceinline__ float tanhf2(float x) {
  float e = __expf(2.f * x);
  return 1.f - 2.f / (e + 1.f);
}

// ---------------------------------------------------------------------------
// Phase 0: prepack W_hh into per-THREAD CONTIGUOUS f16x2 streams (r11 layout,
// passed correctness).  Thread j (u=j>>1, kh=j&1) owns gate rows {u,256+u,
// 512+u} over k-half [128kh,128kh+128); dword G*64+d = W[G*256+u][128kh+2d..].
// ---------------------------------------------------------------------------
__global__ void prepack_whh(const float* __restrict__ Whh, u32* __restrict__ Wp2) {
  int id = blockIdx.x * 256 + threadIdx.x;  // [0, 512*192)
  int j = id / 192;
  int rem = id - j * 192;
  int G = rem >> 6, d = rem & 63;
  int u = j >> 1, kh = j & 1;
  const float* p = Whh + (size_t)(G * 256 + u) * HH + 128 * kh + 2 * d;
  Wp2[id] = pk2(p[0], p[1]);
}

// ---------------------------------------------------------------------------
// Phase 1: gi = x @ W_ih^T + b_ih (+ b_hh folded for r,z), f16. (unchanged)
// ---------------------------------------------------------------------------
__device__ __forceinline__ f32x16v zero16() {
  f32x16v z;
#pragma unroll
  for (int i = 0; i < 16; ++i) z[i] = 0.f;
  return z;
}

__global__ __launch_bounds__(256, 2) void gemm_gi(
    const float* __restrict__ x, const float* __restrict__ Wih,
    const float* __restrict__ bih, const float* __restrict__ bhh,
    f16* __restrict__ gi) {
  __shared__ u32 bl[16384];  // 128 rows x 128 dwords (f16x2) = 64KB
  const int tid = threadIdx.x;
  const int lane = tid & 63;
  const int wv = tid >> 6;
  const int wr = wv >> 1, wc = wv & 1;
  const int l31 = lane & 31, lh = lane >> 5;
  const int m0 = blockIdx.x << 7;

  u32x4v afr[2][16];
#pragma unroll
  for (int fr = 0; fr < 2; ++fr) {
#pragma unroll
    for (int km = 0; km < 16; ++km) {
      int row = m0 + wr * 64 + fr * 32 + l31;
      int k0 = km * 16 + lh * 8;
      const f32x4v* p = (const f32x4v*)(x + (size_t)row * 256 + k0);
      f32x4v u = p[0], v = p[1];
      u32x4v t;
      t.x = pk2(u.x, u.y); t.y = pk2(u.z, u.w);
      t.z = pk2(v.x, v.y); t.w = pk2(v.z, v.w);
      afr[fr][km] = t;
    }
  }

  for (int nt = 0; nt < 6; ++nt) {
    const int n0 = nt << 7;
#pragma unroll
    for (int it = 0; it < 32; ++it) {
      int flat = it * 256 + tid;
      int r = flat >> 6;
      int q = flat & 63;
      f32x4v f = *(const f32x4v*)(Wih + (size_t)(n0 + r) * 256 + 4 * q);
      u32x2v pw;
      pw.x = pk2(f.x, f.y);
      pw.y = pk2(f.z, f.w);
      int wd = 2 * q;
      *(u32x2v*)&bl[r * 128 + (wd ^ ((r & 15) << 2))] = pw;
    }
    __syncthreads();

    f32x16v acc00 = zero16(), acc01 = zero16(), acc10 = zero16(), acc11 = zero16();
#pragma unroll
    for (int km = 0; km < 16; ++km) {
      int w0 = km * 8 + lh * 4;
      int rc0 = wc * 64 + l31;
      int rc1 = wc * 64 + 32 + l31;
      u32x4v b0 = *(const u32x4v*)&bl[rc0 * 128 + (w0 ^ ((rc0 & 15) << 2))];
      u32x4v b1 = *(const u32x4v*)&bl[rc1 * 128 + (w0 ^ ((rc1 & 15) << 2))];
      h8 a0h = __builtin_bit_cast(h8, afr[0][km]);
      h8 a1h = __builtin_bit_cast(h8, afr[1][km]);
      h8 b0h = __builtin_bit_cast(h8, b0);
      h8 b1h = __builtin_bit_cast(h8, b1);
      acc00 = __builtin_amdgcn_mfma_f32_32x32x16_f16(a0h, b0h, acc00, 0, 0, 0);
      acc10 = __builtin_amdgcn_mfma_f32_32x32x16_f16(a1h, b0h, acc10, 0, 0, 0);
      acc01 = __builtin_amdgcn_mfma_f32_32x32x16_f16(a0h, b1h, acc01, 0, 0, 0);
      acc11 = __builtin_amdgcn_mfma_f32_32x32x16_f16(a1h, b1h, acc11, 0, 0, 0);
    }

#define EPI(ACC, FR, FC)                                                      \
    {                                                                         \
      int gc = n0 + wc * 64 + (FC) * 32 + l31;                                \
      float bias = bih[gc] + (gc < 512 ? bhh[gc] : 0.f);                      \
      _Pragma("unroll")                                                       \
      for (int rg = 0; rg < 16; ++rg) {                                       \
        int gr = m0 + wr * 64 + (FR) * 32 + 4 * lh + (rg & 3) + 8 * (rg >> 2);\
        gi[(size_t)gr * 768 + gc] = (f16)(ACC[rg] + bias);                    \
      }                                                                       \
    }
    EPI(acc00, 0, 0) EPI(acc10, 1, 0) EPI(acc01, 0, 1) EPI(acc11, 1, 1)
#undef EPI
    __syncthreads();
  }
}

// ---------------------------------------------------------------------------
// Phase 2: recurrence, asm-core v2 (r12 — session best).  Weights in PHYSICAL
// v64..v255.  ONE fused asm dot phase: 16 ds_read_b128 of h double-buffered
// through v[56:59]/v[60:63] with counted lgkmcnt(1) waits, interleaved with
// 192 v_dot2_f32_f16 naming weight regs literally; 6 accumulation chains.
// 64 blocks x 512 thr (8 waves, 2/SIMD).  1 barrier/step.
// ---------------------------------------------------------------------------
#define WCLOB_LD \
  "v64","v65","v66","v67","v68","v69","v70","v71", \
  "v72","v73","v74","v75","v76","v77","v78","v79", \
  "v80","v81","v82","v83","v84","v85","v86","v87", \
  "v88","v89","v90","v91","v92","v93","v94","v95", \
  "v96","v97","v98","v99","v100","v101","v102","v103", \
  "v104","v105","v106","v107","v108","v109","v110","v111", \
  "v112","v113","v114","v115","v116","v117","v118","v119", \
  "v120","v121","v122","v123","v124","v125","v126","v127", \
  "v128","v129","v130","v131","v132","v133","v134","v135", \
  "v136","v137","v138","v139","v140","v141","v142","v143", \
  "v144","v145","v146","v147","v148","v149","v150","v151", \
  "v152","v153","v154","v155","v156","v157","v158","v159", \
  "v160","v161","v162","v163","v164","v165","v166","v167", \
  "v168","v169","v170","v171","v172","v173","v174","v175", \
  "v176","v177","v178","v179","v180","v181","v182","v183", \
  "v184","v185","v186","v187","v188","v189","v190","v191", \
  "v192","v193","v194","v195","v196","v197","v198","v199", \
  "v200","v201","v202","v203","v204","v205","v206","v207", \
  "v208","v209","v210","v211","v212","v213","v214","v215", \
  "v216","v217","v218","v219","v220","v221","v222","v223", \
  "v224","v225","v226","v227","v228","v229","v230","v231", \
  "v232","v233","v234","v235","v236","v237","v238","v239", \
  "v240","v241","v242","v243","v244","v245","v246","v247", \
  "v248","v249","v250","v251","v252","v253","v254","v255"

#define WCLOB "v56","v57","v58","v59","v60","v61","v62","v63", WCLOB_LD

#define LD16(A,B,OFF) "global_load_dwordx4 v[" #A ":" #B "], %0, off offset:" #OFF "\n\t"

#define RD_A(OFF) "ds_read_b128 v[56:59], %6 offset:" #OFF "\n\t"
#define RD_B(OFF) "ds_read_b128 v[60:63], %6 offset:" #OFF "\n\t"
#define WT1 "s_waitcnt lgkmcnt(1)\n\t"
#define WT0 "s_waitcnt lgkmcnt(0)\n\t"

// 12 dots: chains %0/%1 = r-gate, %2/%3 = z-gate, %4/%5 = n-gate
#define GRP(Q0,Q1,Q2,Q3, R0,R1,R2,R3, Z0,Z1,Z2,Z3, N0,N1,N2,N3) \
  "v_dot2_f32_f16 %0, v" #R0 ", v" #Q0 ", %0\n\t" \
  "v_dot2_f32_f16 %2, v" #Z0 ", v" #Q0 ", %2\n\t" \
  "v_dot2_f32_f16 %4, v" #N0 ", v" #Q0 ", %4\n\t" \
  "v_dot2_f32_f16 %1, v" #R1 ", v" #Q1 ", %1\n\t" \
  "v_dot2_f32_f16 %3, v" #Z1 ", v" #Q1 ", %3\n\t" \
  "v_dot2_f32_f16 %5, v" #N1 ", v" #Q1 ", %5\n\t" \
  "v_dot2_f32_f16 %0, v" #R2 ", v" #Q2 ", %0\n\t" \
  "v_dot2_f32_f16 %2, v" #Z2 ", v" #Q2 ", %2\n\t" \
  "v_dot2_f32_f16 %4, v" #N2 ", v" #Q2 ", %4\n\t" \
  "v_dot2_f32_f16 %1, v" #R3 ", v" #Q3 ", %1\n\t" \
  "v_dot2_f32_f16 %3, v" #Z3 ", v" #Q3 ", %3\n\t" \
  "v_dot2_f32_f16 %5, v" #N3 ", v" #Q3 ", %5\n\t"

__global__ __launch_bounds__(512, 2) void recur(
    const u32* __restrict__ Wp2, const f16* __restrict__ gi,
    const float* __restrict__ states, const float* __restrict__ mask,
    const float* __restrict__ bhh_g, float* __restrict__ out) {
  const int b = blockIdx.x;
  const int j = threadIdx.x;
  const int u = j >> 1;
  const int kh = j & 1;

  __shared__ __align__(16) u32 hbuf[2][128];   // h as f16x2
  __shared__ float mlds[TT];                   // mask row, 4 KB

  const float bhn = bhh_g[512 + u];   // r,z biases folded into gi by gemm

  const float* mk = mask + b * TT;
  const f16* gcur = gi + (size_t)b * TT * GG + u;
  float* outb = out + (size_t)b * TT * HH;

  for (int i = j; i < TT; i += 512) mlds[i] = mk[i];

  float hreg = states[b * HH + u] * mk[0];   // both lanes of the pair
  if (kh == 0) ((f16*)hbuf[0])[u] = (f16)hreg;

  // ---- load 192 weight dwords into PHYSICAL v64..v255 ----
  {
    u64 wa = (u64)(Wp2 + (size_t)j * 192);
    asm volatile(
      LD16(64,67,0)    LD16(68,71,16)   LD16(72,75,32)   LD16(76,79,48)
      LD16(80,83,64)   LD16(84,87,80)   LD16(88,91,96)   LD16(92,95,112)
      LD16(96,99,128)  LD16(100,103,144) LD16(104,107,160) LD16(108,111,176)
      LD16(112,115,192) LD16(116,119,208) LD16(120,123,224) LD16(124,127,240)
      LD16(128,131,256) LD16(132,135,272) LD16(136,139,288) LD16(140,143,304)
      LD16(144,147,320) LD16(148,151,336) LD16(152,155,352) LD16(156,159,368)
      LD16(160,163,384) LD16(164,167,400) LD16(168,171,416) LD16(172,175,432)
      LD16(176,179,448) LD16(180,183,464) LD16(184,187,480) LD16(188,191,496)
      LD16(192,195,512) LD16(196,199,528) LD16(200,203,544) LD16(204,207,560)
      LD16(208,211,576) LD16(212,215,592) LD16(216,219,608) LD16(220,223,624)
      LD16(224,227,640) LD16(228,231,656) LD16(232,235,672) LD16(236,239,688)
      LD16(240,243,704) LD16(244,247,720) LD16(248,251,736) LD16(252,255,752)
      "s_waitcnt vmcnt(0)\n\t"
      :: "v"(wa) : WCLOB_LD, "memory");
  }
  __syncthreads();

  float nh_prev = 0.f;

  for (int t = 0; t < TT; ++t) {
    if (t > 0 && kh == 0) outb[(size_t)(t - 1) * HH + u] = nh_prev;
    f16 gr_c = gcur[0], gz_c = gcur[256], gn_c = gcur[512];

    u32 lds_addr = (u32)(size_t)(&hbuf[t & 1][kh << 6]);
    float ar0 = 0.f, ar1 = 0.f, az0 = 0.f, az1 = 0.f, an0 = 0.f, an1 = 0.f;

    asm volatile(
      WT0                      // drain C-side DS ops so counting is exact
      RD_A(0) RD_B(16)
      WT1 GRP(56,57,58,59,  64,65,66,67,    128,129,130,131, 192,193,194,195) RD_A(32)
      WT1 GRP(60,61,62,63,  68,69,70,71,    132,133,134,135, 196,197,198,199) RD_B(48)
      WT1 GRP(56,57,58,59,  72,73,74,75,    136,137,138,139, 200,201,202,203) RD_A(64)
      WT1 GRP(60,61,62,63,  76,77,78,79,    140,141,142,143, 204,205,206,207) RD_B(80)
      WT1 GRP(56,57,58,59,  80,81,82,83,    144,145,146,147, 208,209,210,211) RD_A(96)
      WT1 GRP(60,61,62,63,  84,85,86,87,    148,149,150,151, 212,213,214,215) RD_B(112)
      WT1 GRP(56,57,58,59,  88,89,90,91,    152,153,154,155, 216,217,218,219) RD_A(128)
      WT1 GRP(60,61,62,63,  92,93,94,95,    156,157,158,159, 220,221,222,223) RD_B(144)
      WT1 GRP(56,57,58,59,  96,97,98,99,    160,161,162,163, 224,225,226,227) RD_A(160)
      WT1 GRP(60,61,62,63,  100,101,102,103, 164,165,166,167, 228,229,230,231) RD_B(176)
      WT1 GRP(56,57,58,59,  104,105,106,107, 168,169,170,171, 232,233,234,235) RD_A(192)
      WT1 GRP(60,61,62,63,  108,109,110,111, 172,173,174,175, 236,237,238,239) RD_B(208)
      WT1 GRP(56,57,58,59,  112,113,114,115, 176,177,178,179, 240,241,242,243) RD_A(224)
      WT1 GRP(60,61,62,63,  116,117,118,119, 180,181,182,183, 244,245,246,247) RD_B(240)
      WT1 GRP(56,57,58,59,  120,121,122,123, 184,185,186,187, 248,249,250,251)
      WT0 GRP(60,61,62,63,  124,125,126,127, 188,189,190,191, 252,253,254,255)
      : "+v"(ar0), "+v"(ar1), "+v"(az0), "+v"(az1), "+v"(an0), "+v"(an1)
      : "v"(lds_addr)
      : WCLOB, "memory");

    const float mt = mlds[t];

    float ar = ar0 + ar1, az = az0 + az1, an = an0 + an1;
    // pair-reduce across the two k-halves (lane 2u <-> 2u+1)
    float ghr = ar + dpp_x1(ar);
    float ghz = az + dpp_x1(az);
    float ghn = an + dpp_x1(an);

    float r = sigf((float)gr_c + ghr);
    float z = sigf((float)gz_c + ghz);
    float n = tanhf2((float)gn_c + r * (ghn + bhn));
    float nh = z * (hreg - n) + n;            // (1-z)n + z h
    float hnew = hreg + mt * (nh - hreg);     // mask blend
    nh_prev = nh;
    hreg = hnew;
    if (kh == 0) ((f16*)hbuf[(t + 1) & 1])[u] = (f16)hnew;
    gcur += GG;
    __syncthreads();
  }

  if (kh == 0) {
    outb[(size_t)(TT - 1) * HH + u] = nh_prev;
    out[(size_t)BB * TT * HH + b * HH + u] = hreg;  // final state
  }
}

extern "C" void kernel_launch(void* const* d_in, const int* in_sizes, int n_in,
                              void* d_out, int out_size, void* d_ws, size_t ws_size,
                              hipStream_t stream) {
  const float* x      = (const float*)d_in[0];
  const float* states = (const float*)d_in[1];
  const float* mask   = (const float*)d_in[2];
  const float* W_ih   = (const float*)d_in[3];
  const float* W_hh   = (const float*)d_in[4];
  const float* b_ih   = (const float*)d_in[5];
  const float* b_hh   = (const float*)d_in[6];
  float* out = (float*)d_out;

  char* ws = (char*)d_ws;
  f16* gi = (f16*)ws;
  u32* Wp2 = (u32*)(ws + GI_BYTES);

  prepack_whh<<<dim3(384), dim3(256), 0, stream>>>(W_hh, Wp2);
  gemm_gi<<<dim3(512), dim3(256), 0, stream>>>(x, W_ih, b_ih, b_hh, gi);
  recur<<<dim3(64), dim3(512), 0, stream>>>(Wp2, gi, states, mask, b_hh, out);
}